// Round 8
// baseline (177.497 us; speedup 1.0000x reference)
//
#include <hip/hip_runtime.h>
#include <hip/hip_fp16.h>
#include <math.h>

// Problem constants
#define NB 392      // n = b*oh*ow = 2*14*14
#define NI 288      // K*K*B = 9*32
#define NC 32       // C
#define NQ 16       // PSIZE
#define CQ 512      // NC*NQ
#define CH 544      // B*(PSIZE+1)
#define EPSV 1e-6f
#define NPAD 448    // n padded to 7 tiles of 64 rows

// element counts
#define P16E (NI*NPAD*32)     // p16[i][n][32k]  fp16, k>=16 zero-pad
#define W16E (NI*CQ*32)       // w16[i][cq][32k] fp16, k>=16 zero-pad
#define AFACE (NB*NI)         // afac floats

// ws float offsets
#define OFF_AFAC 0
#define OFF_P16  (AFACE)
#define OFF_W16  (OFF_P16 + P16E/2)
#define OFF_VOT  (OFF_W16 + W16E/2)

// out layout (floats)
#define OFF_AOUT 200704       // NB*CQ
#define OFF_CAT  213248       // OFF_AOUT + NB*NC

// routing block shape: 12 waves x (2 g-halves) = 24 i-streams x 12 steps = 288
#define RT_THREADS 768
#define RT_WAVES 12

typedef _Float16 v8h __attribute__((ext_vector_type(8)));
typedef float v4f __attribute__((ext_vector_type(4)));

// ---------------------------------------------------------------------------
// Gather from x via the unfold channel-major reinterpret.
__device__ __forceinline__ float gather_x(const float* __restrict__ x, int n, int j) {
    int c_idx = j / 9;
    int rem = j - c_idx * 9;
    int ki = rem / 3;
    int kj = rem - ki * 3;
    int b_ = n / 196;
    int rest = n - b_ * 196;
    int yy = rest / 14;
    int xx = rest - yy * 14;
    int iy = yy + ki - 1;
    int ix = xx + kj - 1;
    float v = 0.f;
    if ((unsigned)iy < 14u && (unsigned)ix < 14u)
        v = x[((b_ * 14 + iy) * 14 + ix) * CH + c_idx];
    return v;
}

// p16 (fp16, padded) + afac (fp32): grid-stride elementwise.
__global__ __launch_bounds__(256) void prep_pa(const float* __restrict__ x,
                                               ushort* __restrict__ p16,
                                               float* __restrict__ afac) {
    int tid = blockIdx.x * 256 + threadIdx.x;
    if (tid < P16E) {
        int k = tid & 31;
        int i = tid / (NPAD * 32);
        int n = (tid >> 5) - i * NPAD;
        float v = 0.f;
        if (n < NB && k < 16) {
            int j = (i >> 5) * CH + (i & 31) * 16 + k;
            v = gather_x(x, n, j);
        }
        p16[tid] = __half_as_ushort(__float2half(v));
    } else if (tid < P16E + AFACE) {
        int t3 = tid - P16E;
        int i = t3 % NI;
        int n = t3 / NI;
        int j = (i >> 5) * CH + 512 + (i & 31);
        float v = gather_x(x, n, j);
        float a = fminf(fmaxf(v, 1e-4f), 1.0f);
        afac[t3] = a / (a + EPSV);
    }
}

// w16[i][cq][32k] = wts[i][cq>>4][k][cq&15] (k<16), via LDS transpose.
__global__ __launch_bounds__(256) void prep_w(const float* __restrict__ wts,
                                              ushort* __restrict__ w16) {
    __shared__ float wl[8192];   // 32 KB: wts[i] tile, [c][p][q] flat
    int i = blockIdx.x;
    int t = threadIdx.x;
    const float4* src = (const float4*)(wts + (size_t)i * 8192);
#pragma unroll
    for (int it = 0; it < 8; ++it)
        *(float4*)&wl[(it * 256 + t) * 4] = src[it * 256 + t];
    __syncthreads();
    uint* dst = (uint*)(w16 + (size_t)i * 16384);
    for (int it = 0; it < 32; ++it) {
        int idx = it * 256 + t;          // uint index = cq*16 + kpair
        int kpair = idx & 15;
        int cq = idx >> 4;
        uint val = 0;
        if (kpair < 8) {
            int base = (cq >> 4) * 256 + (cq & 15);
            __half2 h = __floats2half2_rn(wl[base + (2 * kpair) * 16],
                                          wl[base + (2 * kpair + 1) * 16]);
            val = *(uint*)&h;
        }
        dst[idx] = val;
    }
}

// ---------------------------------------------------------------------------
// votes via MFMA, M=64 blocking, ct-chunked staging (17 KB LDS).
__global__ __launch_bounds__(256) void votes_k(const ushort* __restrict__ p16,
                                               const ushort* __restrict__ w16,
                                               ushort* __restrict__ votes) {
    __shared__ ushort tile[64 * 136];   // 17 KB
    int mtt = blockIdx.x;         // 0..6
    int i = blockIdx.y;           // 0..287
    int t = threadIdx.x;
    int wv = t >> 6;
    int l = t & 63;
    int col = l & 15;
    int quad = l >> 4;

    int row_a = mtt * 64 + wv * 16 + col;
    v8h av = *(const v8h*)(p16 + ((size_t)(i * NPAD + row_a) << 5) + (quad << 3));

    for (int ch = 0; ch < 4; ++ch) {
#pragma unroll
        for (int c8 = 0; c8 < 8; ++c8) {
            int ct = ch * 8 + c8;
            v8h bv = *(const v8h*)(w16 + ((size_t)(i * CQ + ct * 16 + col) << 5) + (quad << 3));
            v4f acc = {0.f, 0.f, 0.f, 0.f};
            acc = __builtin_amdgcn_mfma_f32_16x16x32_f16(av, bv, acc, 0, 0, 0);
#pragma unroll
            for (int r = 0; r < 4; ++r)
                tile[(wv * 16 + quad * 4 + r) * 136 + c8 * 16 + col] =
                    __half_as_ushort(__float2half(acc[r]));
        }
        __syncthreads();
#pragma unroll
        for (int k = 0; k < 4; ++k) {
            int idx = k * 256 + t;
            int row = idx >> 4;
            int off = idx & 15;
            int n_out = mtt * 64 + row;
            if (n_out < NB) {
                uint4 d = *(const uint4*)&tile[row * 136 + off * 8];
                *(uint4*)(votes + (((size_t)n_out * NI + i) << 9) + ch * 128 + off * 8) = d;
            }
        }
        __syncthreads();
    }
}

// ---------------------------------------------------------------------------
// Fused dynamic routing, 3 passes. Block = n, 768 threads (12 waves).
// Lane: c = l&31, g = l>>5; wave wv step s handles i = s*24 + wv*2 + g.
// Agreement dot fully in-lane; b_ij linear in history -> only cumulative vjr.
// Scratch (sred, vj) uses layout [q*32 + c]: partial writes and vjr reloads
// are bank-conflict-free (bank == c), fixing the 1.0M SQ_LDS_BANK_CONFLICT
// of the [c][q]-float4 layout. 768-thread blocks double per-CU residency
// (2 blocks = 24 waves/CU) vs 512-thread (12 waves/CU) -- latency-bound fix.
__global__ __launch_bounds__(RT_THREADS, 6) void routing_k(const ushort* __restrict__ votes,
                                                           const float* __restrict__ afac,
                                                           float* __restrict__ out) {
    __shared__ float afs[NI];
    __shared__ float sred[RT_WAVES * CQ];   // 24 KB, [group][q*32+c]
    __shared__ float vj[CQ];                // [q*32+c]
    __shared__ float aout_s[NC];

    int n = blockIdx.x;
    int t = threadIdx.x;
    int wv = t >> 6;      // 0..11
    int l = t & 63;
    int c = l & 31;
    int g = l >> 5;

    if (t < NI) afs[t] = afac[n * NI + t];
    __syncthreads();

    const ushort* vb = votes + (size_t)n * NI * CQ;
    float vjr[16];    // cumulative sum of vj over past iters
    float sreg[16];

    for (int iter = 0; iter < 3; ++iter) {
#pragma unroll
        for (int q = 0; q < 16; ++q) sreg[q] = 0.f;

        // depth-2 prefetch: rows for s=0,1   (i = s*24 + wv*2 + g)
        const uint4* r0 = (const uint4*)(vb + ((size_t)(0 * 24 + wv * 2 + g) << 9) + (c << 4));
        uint4 a0 = r0[0], a1 = r0[1];
        const uint4* r1 = (const uint4*)(vb + ((size_t)(1 * 24 + wv * 2 + g) << 9) + (c << 4));
        uint4 b0 = r1[0], b1 = r1[1];

#pragma clang loop unroll_count(2)
        for (int s = 0; s < 12; ++s) {
            int i = s * 24 + wv * 2 + g;
            uint4 c0 = a0, c1 = a1;
            a0 = b0; a1 = b1;
            if (s + 2 < 12) {
                const uint4* rn = (const uint4*)(vb + ((size_t)((s + 2) * 24 + wv * 2 + g) << 9) + (c << 4));
                b0 = rn[0]; b1 = rn[1];
            }
            float vt[16];
            {
                float2 f;
                f = __half22float2(*(const __half2*)&c0.x); vt[0] = f.x;  vt[1] = f.y;
                f = __half22float2(*(const __half2*)&c0.y); vt[2] = f.x;  vt[3] = f.y;
                f = __half22float2(*(const __half2*)&c0.z); vt[4] = f.x;  vt[5] = f.y;
                f = __half22float2(*(const __half2*)&c0.w); vt[6] = f.x;  vt[7] = f.y;
                f = __half22float2(*(const __half2*)&c1.x); vt[8] = f.x;  vt[9] = f.y;
                f = __half22float2(*(const __half2*)&c1.y); vt[10] = f.x; vt[11] = f.y;
                f = __half22float2(*(const __half2*)&c1.z); vt[12] = f.x; vt[13] = f.y;
                f = __half22float2(*(const __half2*)&c1.w); vt[14] = f.x; vt[15] = f.y;
            }
            float cij;
            if (iter == 0) {
                cij = afs[i] * (1.0f / 32.0f);
            } else {
                float ah = 0.f;
#pragma unroll
                for (int q = 0; q < 16; ++q) ah += vt[q] * vjr[q];
                float e = __expf(ah);   // |b| <= ~0.7: no max-sub needed
                float ssum = e;
                ssum += __shfl_xor(ssum, 1);
                ssum += __shfl_xor(ssum, 2);
                ssum += __shfl_xor(ssum, 4);
                ssum += __shfl_xor(ssum, 8);
                ssum += __shfl_xor(ssum, 16);
                cij = e * __builtin_amdgcn_rcpf(ssum) * afs[i];
            }
#pragma unroll
            for (int q = 0; q < 16; ++q) sreg[q] += cij * vt[q];
        }

        // fold the two g-halves in-wave, then write 12 partial groups.
        // Layout [q*32+c]: lane c writes bank c -> conflict-free scalar stores.
#pragma unroll
        for (int q = 0; q < 16; ++q) sreg[q] += __shfl_xor(sreg[q], 32);
        if (g == 0) {
            float* sw = &sred[wv * CQ + c];
#pragma unroll
            for (int q = 0; q < 16; ++q) sw[q * 32] = sreg[q];
        }
        __syncthreads();
        if (t < CQ) {
            float ssum = 0.f;
#pragma unroll
            for (int k = 0; k < RT_WAVES; ++k) ssum += sred[k * CQ + t];
            sred[t] = ssum;   // per-thread column: safe
        }
        __syncthreads();

        // squash (threads 0..31, one c each; element (c,q) at sred[q*32+c])
        if (t < NC) {
            float s2 = 0.f;
#pragma unroll
            for (int q = 0; q < 16; ++q) {
                float s = sred[q * 32 + t];
                s2 += s * s;
            }
            float f = (s2 / (1.f + s2)) / sqrtf(s2 + EPSV);
            float vn2 = 0.f;
#pragma unroll
            for (int q = 0; q < 16; ++q) {
                float v = f * sred[q * 32 + t];
                vj[q * 32 + t] = v;
                vn2 += v * v;
            }
            if (iter == 2) {
                float ao = sqrtf(vn2 + EPSV);
                ao = fminf(fmaxf(ao, 1e-4f), 1.f - 1e-4f);
                aout_s[t] = ao;
            }
        }
        __syncthreads();
        if (iter < 2) {
#pragma unroll
            for (int q = 0; q < 16; ++q) {
                float v = vj[q * 32 + c];   // bank c + broadcast pair: free
                vjr[q] = (iter == 0) ? v : vjr[q] + v;
            }
        }
    }

    // outputs: p_out, a_out, concat(out).  canonical idx t: c=t>>4, q=t&15
    if (t < CQ) {
        float v = vj[(t & 15) * 32 + (t >> 4)];
        out[(size_t)n * CQ + t] = v;
        out[OFF_CAT + (size_t)n * 544 + t] = v;
    }
    if (t < NC) {
        float ao = aout_s[t];
        out[OFF_AOUT + n * 32 + t] = ao;
        out[OFF_CAT + (size_t)n * 544 + 512 + t] = ao;
    }
}

// ---------------------------------------------------------------------------
extern "C" void kernel_launch(void* const* d_in, const int* in_sizes, int n_in,
                              void* d_out, int out_size, void* d_ws, size_t ws_size,
                              hipStream_t stream) {
    const float* x = (const float*)d_in[0];
    const float* wts = (const float*)d_in[1];
    float* out = (float*)d_out;
    float* ws = (float*)d_ws;

    float* afac = ws + OFF_AFAC;
    ushort* p16 = (ushort*)(ws + OFF_P16);
    ushort* w16 = (ushort*)(ws + OFF_W16);
    ushort* votes = (ushort*)(ws + OFF_VOT);

    hipLaunchKernelGGL(prep_w, dim3(NI), dim3(256), 0, stream, wts, w16);
    hipLaunchKernelGGL(prep_pa, dim3((P16E + AFACE + 255) / 256), dim3(256), 0, stream,
                       x, p16, afac);
    hipLaunchKernelGGL(votes_k, dim3(7, NI), dim3(256), 0, stream,
                       p16, w16, votes);
    hipLaunchKernelGGL(routing_k, dim3(NB), dim3(RT_THREADS), 0, stream,
                       votes, afac, out);
}

// Round 9
// 159.357 us; speedup vs baseline: 1.1138x; 1.1138x over previous
//
#include <hip/hip_runtime.h>
#include <hip/hip_fp16.h>
#include <math.h>

// Problem constants
#define NB 392      // n = b*oh*ow = 2*14*14
#define NI 288      // K*K*B = 9*32
#define NC 32       // C
#define NQ 16       // PSIZE
#define CQ 512      // NC*NQ
#define CH 544      // B*(PSIZE+1)
#define EPSV 1e-6f
#define NPAD 448    // n padded to 7 tiles of 64 rows

// element counts
#define P16E (NI*NPAD*32)     // p16[i][n][32k]  fp16, k>=16 zero-pad
#define W16E (NI*CQ*32)       // w16[i][cq][32k] fp16, k>=16 zero-pad
#define AFACE (NB*NI)         // afac floats

// ws float offsets
#define OFF_AFAC 0
#define OFF_P16  (AFACE)
#define OFF_W16  (OFF_P16 + P16E/2)
#define OFF_VOT  (OFF_W16 + W16E/2)

// out layout (floats)
#define OFF_AOUT 200704       // NB*CQ
#define OFF_CAT  213248       // OFF_AOUT + NB*NC

// routing block shape: 12 waves x (2 g-halves) = 24 i-streams x 12 steps = 288
#define RT_THREADS 768
#define RT_WAVES 12

typedef _Float16 v8h __attribute__((ext_vector_type(8)));
typedef float v4f __attribute__((ext_vector_type(4)));

// ---------------------------------------------------------------------------
// Gather from x via the unfold channel-major reinterpret.
__device__ __forceinline__ float gather_x(const float* __restrict__ x, int n, int j) {
    int c_idx = j / 9;
    int rem = j - c_idx * 9;
    int ki = rem / 3;
    int kj = rem - ki * 3;
    int b_ = n / 196;
    int rest = n - b_ * 196;
    int yy = rest / 14;
    int xx = rest - yy * 14;
    int iy = yy + ki - 1;
    int ix = xx + kj - 1;
    float v = 0.f;
    if ((unsigned)iy < 14u && (unsigned)ix < 14u)
        v = x[((b_ * 14 + iy) * 14 + ix) * CH + c_idx];
    return v;
}

// p16 (fp16, padded) + afac (fp32): grid-stride elementwise.
__global__ __launch_bounds__(256) void prep_pa(const float* __restrict__ x,
                                               ushort* __restrict__ p16,
                                               float* __restrict__ afac) {
    int tid = blockIdx.x * 256 + threadIdx.x;
    if (tid < P16E) {
        int k = tid & 31;
        int i = tid / (NPAD * 32);
        int n = (tid >> 5) - i * NPAD;
        float v = 0.f;
        if (n < NB && k < 16) {
            int j = (i >> 5) * CH + (i & 31) * 16 + k;
            v = gather_x(x, n, j);
        }
        p16[tid] = __half_as_ushort(__float2half(v));
    } else if (tid < P16E + AFACE) {
        int t3 = tid - P16E;
        int i = t3 % NI;
        int n = t3 / NI;
        int j = (i >> 5) * CH + 512 + (i & 31);
        float v = gather_x(x, n, j);
        float a = fminf(fmaxf(v, 1e-4f), 1.0f);
        afac[t3] = a / (a + EPSV);
    }
}

// w16[i][cq][32k] = wts[i][cq>>4][k][cq&15] (k<16), via LDS transpose.
__global__ __launch_bounds__(256) void prep_w(const float* __restrict__ wts,
                                              ushort* __restrict__ w16) {
    __shared__ float wl[8192];   // 32 KB: wts[i] tile, [c][p][q] flat
    int i = blockIdx.x;
    int t = threadIdx.x;
    const float4* src = (const float4*)(wts + (size_t)i * 8192);
#pragma unroll
    for (int it = 0; it < 8; ++it)
        *(float4*)&wl[(it * 256 + t) * 4] = src[it * 256 + t];
    __syncthreads();
    uint* dst = (uint*)(w16 + (size_t)i * 16384);
    for (int it = 0; it < 32; ++it) {
        int idx = it * 256 + t;          // uint index = cq*16 + kpair
        int kpair = idx & 15;
        int cq = idx >> 4;
        uint val = 0;
        if (kpair < 8) {
            int base = (cq >> 4) * 256 + (cq & 15);
            __half2 h = __floats2half2_rn(wl[base + (2 * kpair) * 16],
                                          wl[base + (2 * kpair + 1) * 16]);
            val = *(uint*)&h;
        }
        dst[idx] = val;
    }
}

// ---------------------------------------------------------------------------
// votes via MFMA, M=64 blocking, ct-chunked staging (17 KB LDS).
__global__ __launch_bounds__(256) void votes_k(const ushort* __restrict__ p16,
                                               const ushort* __restrict__ w16,
                                               ushort* __restrict__ votes) {
    __shared__ ushort tile[64 * 136];   // 17 KB
    int mtt = blockIdx.x;         // 0..6
    int i = blockIdx.y;           // 0..287
    int t = threadIdx.x;
    int wv = t >> 6;
    int l = t & 63;
    int col = l & 15;
    int quad = l >> 4;

    int row_a = mtt * 64 + wv * 16 + col;
    v8h av = *(const v8h*)(p16 + ((size_t)(i * NPAD + row_a) << 5) + (quad << 3));

    for (int ch = 0; ch < 4; ++ch) {
#pragma unroll
        for (int c8 = 0; c8 < 8; ++c8) {
            int ct = ch * 8 + c8;
            v8h bv = *(const v8h*)(w16 + ((size_t)(i * CQ + ct * 16 + col) << 5) + (quad << 3));
            v4f acc = {0.f, 0.f, 0.f, 0.f};
            acc = __builtin_amdgcn_mfma_f32_16x16x32_f16(av, bv, acc, 0, 0, 0);
#pragma unroll
            for (int r = 0; r < 4; ++r)
                tile[(wv * 16 + quad * 4 + r) * 136 + c8 * 16 + col] =
                    __half_as_ushort(__float2half(acc[r]));
        }
        __syncthreads();
#pragma unroll
        for (int k = 0; k < 4; ++k) {
            int idx = k * 256 + t;
            int row = idx >> 4;
            int off = idx & 15;
            int n_out = mtt * 64 + row;
            if (n_out < NB) {
                uint4 d = *(const uint4*)&tile[row * 136 + off * 8];
                *(uint4*)(votes + (((size_t)n_out * NI + i) << 9) + ch * 128 + off * 8) = d;
            }
        }
        __syncthreads();
    }
}

// ---------------------------------------------------------------------------
// Fused dynamic routing, 3 passes. Block = n, 768 threads (12 waves).
// Lane: c = l&31, g = l>>5; wave wv step s handles i = s*24 + wv*2 + g.
// Agreement dot fully in-lane; b_ij linear in history -> only cumulative vjr.
// Scratch layout [q*32+c]: bank == c -> conflict-free (round 8: 1.0M -> 94k).
// NOTE: no min-waves arg in __launch_bounds__ -- round 8's (768,6) squeezed
// the allocator to 40 VGPR and spilled the prefetch buffers to scratch
// (WRITE_SIZE 30 MB, dur 48->76 us). Default lets it sit at ~64-84 VGPR,
// still 2 blocks/CU (24 waves) since LDS (28 KB) and waves cap allow it.
__global__ __launch_bounds__(RT_THREADS) void routing_k(const ushort* __restrict__ votes,
                                                        const float* __restrict__ afac,
                                                        float* __restrict__ out) {
    __shared__ float afs[NI];
    __shared__ float sred[RT_WAVES * CQ];   // 24 KB, [group][q*32+c]
    __shared__ float vj[CQ];                // [q*32+c]
    __shared__ float aout_s[NC];

    int n = blockIdx.x;
    int t = threadIdx.x;
    int wv = t >> 6;      // 0..11
    int l = t & 63;
    int c = l & 31;
    int g = l >> 5;

    if (t < NI) afs[t] = afac[n * NI + t];
    __syncthreads();

    const ushort* vb = votes + (size_t)n * NI * CQ;
    float vjr[16];    // cumulative sum of vj over past iters
    float sreg[16];

    for (int iter = 0; iter < 3; ++iter) {
#pragma unroll
        for (int q = 0; q < 16; ++q) sreg[q] = 0.f;

        // depth-2 prefetch: rows for s=0,1   (i = s*24 + wv*2 + g)
        const uint4* r0 = (const uint4*)(vb + ((size_t)(0 * 24 + wv * 2 + g) << 9) + (c << 4));
        uint4 a0 = r0[0], a1 = r0[1];
        const uint4* r1 = (const uint4*)(vb + ((size_t)(1 * 24 + wv * 2 + g) << 9) + (c << 4));
        uint4 b0 = r1[0], b1 = r1[1];

#pragma clang loop unroll_count(2)
        for (int s = 0; s < 12; ++s) {
            int i = s * 24 + wv * 2 + g;
            uint4 c0 = a0, c1 = a1;
            a0 = b0; a1 = b1;
            if (s + 2 < 12) {
                const uint4* rn = (const uint4*)(vb + ((size_t)((s + 2) * 24 + wv * 2 + g) << 9) + (c << 4));
                b0 = rn[0]; b1 = rn[1];
            }
            float vt[16];
            {
                float2 f;
                f = __half22float2(*(const __half2*)&c0.x); vt[0] = f.x;  vt[1] = f.y;
                f = __half22float2(*(const __half2*)&c0.y); vt[2] = f.x;  vt[3] = f.y;
                f = __half22float2(*(const __half2*)&c0.z); vt[4] = f.x;  vt[5] = f.y;
                f = __half22float2(*(const __half2*)&c0.w); vt[6] = f.x;  vt[7] = f.y;
                f = __half22float2(*(const __half2*)&c1.x); vt[8] = f.x;  vt[9] = f.y;
                f = __half22float2(*(const __half2*)&c1.y); vt[10] = f.x; vt[11] = f.y;
                f = __half22float2(*(const __half2*)&c1.z); vt[12] = f.x; vt[13] = f.y;
                f = __half22float2(*(const __half2*)&c1.w); vt[14] = f.x; vt[15] = f.y;
            }
            float cij;
            if (iter == 0) {
                cij = afs[i] * (1.0f / 32.0f);
            } else {
                float ah = 0.f;
#pragma unroll
                for (int q = 0; q < 16; ++q) ah += vt[q] * vjr[q];
                float e = __expf(ah);   // |b| <= ~0.7: no max-sub needed
                float ssum = e;
                ssum += __shfl_xor(ssum, 1);
                ssum += __shfl_xor(ssum, 2);
                ssum += __shfl_xor(ssum, 4);
                ssum += __shfl_xor(ssum, 8);
                ssum += __shfl_xor(ssum, 16);
                cij = e * __builtin_amdgcn_rcpf(ssum) * afs[i];
            }
#pragma unroll
            for (int q = 0; q < 16; ++q) sreg[q] += cij * vt[q];
        }

        // fold the two g-halves in-wave, then write 12 partial groups.
        // Layout [q*32+c]: lane c writes bank c -> conflict-free scalar stores.
#pragma unroll
        for (int q = 0; q < 16; ++q) sreg[q] += __shfl_xor(sreg[q], 32);
        if (g == 0) {
            float* sw = &sred[wv * CQ + c];
#pragma unroll
            for (int q = 0; q < 16; ++q) sw[q * 32] = sreg[q];
        }
        __syncthreads();
        if (t < CQ) {
            float ssum = 0.f;
#pragma unroll
            for (int k = 0; k < RT_WAVES; ++k) ssum += sred[k * CQ + t];
            sred[t] = ssum;   // per-thread column: safe
        }
        __syncthreads();

        // squash (threads 0..31, one c each; element (c,q) at sred[q*32+c])
        if (t < NC) {
            float s2 = 0.f;
#pragma unroll
            for (int q = 0; q < 16; ++q) {
                float s = sred[q * 32 + t];
                s2 += s * s;
            }
            float f = (s2 / (1.f + s2)) / sqrtf(s2 + EPSV);
            float vn2 = 0.f;
#pragma unroll
            for (int q = 0; q < 16; ++q) {
                float v = f * sred[q * 32 + t];
                vj[q * 32 + t] = v;
                vn2 += v * v;
            }
            if (iter == 2) {
                float ao = sqrtf(vn2 + EPSV);
                ao = fminf(fmaxf(ao, 1e-4f), 1.f - 1e-4f);
                aout_s[t] = ao;
            }
        }
        __syncthreads();
        if (iter < 2) {
#pragma unroll
            for (int q = 0; q < 16; ++q) {
                float v = vj[q * 32 + c];   // bank c + broadcast pair: free
                vjr[q] = (iter == 0) ? v : vjr[q] + v;
            }
        }
    }

    // outputs: p_out, a_out, concat(out).  canonical idx t: c=t>>4, q=t&15
    if (t < CQ) {
        float v = vj[(t & 15) * 32 + (t >> 4)];
        out[(size_t)n * CQ + t] = v;
        out[OFF_CAT + (size_t)n * 544 + t] = v;
    }
    if (t < NC) {
        float ao = aout_s[t];
        out[OFF_AOUT + n * 32 + t] = ao;
        out[OFF_CAT + (size_t)n * 544 + 512 + t] = ao;
    }
}

// ---------------------------------------------------------------------------
extern "C" void kernel_launch(void* const* d_in, const int* in_sizes, int n_in,
                              void* d_out, int out_size, void* d_ws, size_t ws_size,
                              hipStream_t stream) {
    const float* x = (const float*)d_in[0];
    const float* wts = (const float*)d_in[1];
    float* out = (float*)d_out;
    float* ws = (float*)d_ws;

    float* afac = ws + OFF_AFAC;
    ushort* p16 = (ushort*)(ws + OFF_P16);
    ushort* w16 = (ushort*)(ws + OFF_W16);
    ushort* votes = (ushort*)(ws + OFF_VOT);

    hipLaunchKernelGGL(prep_w, dim3(NI), dim3(256), 0, stream, wts, w16);
    hipLaunchKernelGGL(prep_pa, dim3((P16E + AFACE + 255) / 256), dim3(256), 0, stream,
                       x, p16, afac);
    hipLaunchKernelGGL(votes_k, dim3(7, NI), dim3(256), 0, stream,
                       p16, w16, votes);
    hipLaunchKernelGGL(routing_k, dim3(NB), dim3(RT_THREADS), 0, stream,
                       votes, afac, out);
}

// Round 10
// 144.336 us; speedup vs baseline: 1.2297x; 1.1041x over previous
//
#include <hip/hip_runtime.h>
#include <hip/hip_fp16.h>
#include <math.h>

// Problem constants
#define NB 392      // n = b*oh*ow = 2*14*14
#define NI 288      // K*K*B = 9*32
#define NC 32       // C
#define NQ 16       // PSIZE
#define CQ 512      // NC*NQ
#define CH 544      // B*(PSIZE+1)
#define EPSV 1e-6f
#define NPAD 448    // n padded to 7 tiles of 64 rows

// element counts
#define P16E (NI*NPAD*32)     // p16[i][n][32k]  fp16, k>=16 zero-pad = 4,128,768
#define W16E (NI*CQ*32)       // w16[i][cq][32k] fp16, k>=16 zero-pad = 4,718,592
#define AFACE (NB*NI)         // afac floats = 112,896

// ws float offsets
#define OFF_AFAC 0
#define OFF_P16  (AFACE)
#define OFF_W16  (OFF_P16 + P16E/2)
#define OFF_VOT  (OFF_W16 + W16E/2)

// out layout (floats)
#define OFF_AOUT 200704       // NB*CQ
#define OFF_CAT  213248       // OFF_AOUT + NB*NC

// routing block shape (round 7's best) + round 9's conflict-free layout
#define RT_THREADS 512
#define RT_WAVES 8

// merged prep grid split
#define PW_BLOCKS (NI*2)              // 576 transpose blocks (i, half-cq)
#define P16_BLOCKS (P16E/8/256)       // 2016 (uint4 stores)
#define AFAC_BLOCKS ((AFACE+255)/256) // 442

typedef _Float16 v8h __attribute__((ext_vector_type(8)));
typedef float v4f __attribute__((ext_vector_type(4)));

// ---------------------------------------------------------------------------
// Gather from x via the unfold channel-major reinterpret.
__device__ __forceinline__ float gather_x(const float* __restrict__ x, int n, int j) {
    int c_idx = j / 9;
    int rem = j - c_idx * 9;
    int ki = rem / 3;
    int kj = rem - ki * 3;
    int b_ = n / 196;
    int rest = n - b_ * 196;
    int yy = rest / 14;
    int xx = rest - yy * 14;
    int iy = yy + ki - 1;
    int ix = xx + kj - 1;
    float v = 0.f;
    if ((unsigned)iy < 14u && (unsigned)ix < 14u)
        v = x[((b_ * 14 + iy) * 14 + ix) * CH + c_idx];
    return v;
}

// ---------------------------------------------------------------------------
// ONE merged prep kernel (one launch; transpose blocks overlap elementwise
// blocks). All global stores are uint4 (16 B) -- the round-9 preps spent
// ~50-60 us on scalar 2-4 B stores and a 288-block grid.
__global__ __launch_bounds__(256) void prep_k(const float* __restrict__ x,
                                              const float* __restrict__ wts,
                                              ushort* __restrict__ p16,
                                              ushort* __restrict__ w16,
                                              float* __restrict__ afac) {
    __shared__ float wl[4096];   // 16 KB (only used by transpose blocks)
    int b = blockIdx.x;
    int t = threadIdx.x;

    if (b < PW_BLOCKS) {
        // w16[i][cq][32k] <- wts[i][c][p][q], cq in [h*256, h*256+256)
        int i = b >> 1, h = b & 1;
        const float4* src = (const float4*)(wts + (size_t)i * 8192 + h * 4096);
#pragma unroll
        for (int it = 0; it < 4; ++it)
            *(float4*)&wl[(it * 256 + t) * 4] = src[it * 256 + t];
        __syncthreads();
        uint4* dst = (uint4*)(w16 + (size_t)i * 16384);   // 4096 uint4 per i
#pragma unroll
        for (int it = 0; it < 4; ++it) {
            int idx = it * 256 + t;          // (cl, m): m covers k = 8m..8m+7
            int cl = idx >> 2;
            int m = idx & 3;
            int cq = h * 256 + cl;
            uint4 val = {0u, 0u, 0u, 0u};
            if (m < 2) {
                int base = (cl >> 4) * 256 + (cl & 15);
                uint v[4];
#pragma unroll
                for (int kk = 0; kk < 4; ++kk) {
                    __half2 hh = __floats2half2_rn(wl[base + (8 * m + 2 * kk) * 16],
                                                   wl[base + (8 * m + 2 * kk + 1) * 16]);
                    v[kk] = *(uint*)&hh;
                }
                val = make_uint4(v[0], v[1], v[2], v[3]);
            }
            dst[cq * 4 + m] = val;
        }
    } else if (b < PW_BLOCKS + P16_BLOCKS) {
        // p16[i][n][32k]: one uint4 (8 halves) per thread
        int idx = (b - PW_BLOCKS) * 256 + t;  // < P16E/8
        int quad = idx & 3;
        int r = idx >> 2;
        int n = r % NPAD;
        int i = r / NPAD;
        uint4 val = {0u, 0u, 0u, 0u};
        if (n < NB && quad < 2) {
            int jb = (i >> 5) * CH + (i & 31) * 16 + quad * 8;
            uint v[4];
#pragma unroll
            for (int kk = 0; kk < 4; ++kk) {
                __half2 hh = __floats2half2_rn(gather_x(x, n, jb + 2 * kk),
                                               gather_x(x, n, jb + 2 * kk + 1));
                v[kk] = *(uint*)&hh;
            }
            val = make_uint4(v[0], v[1], v[2], v[3]);
        }
        *(uint4*)(p16 + (size_t)idx * 8) = val;
    } else {
        int t3 = (b - PW_BLOCKS - P16_BLOCKS) * 256 + t;
        if (t3 < AFACE) {
            int i = t3 % NI;
            int n = t3 / NI;
            int j = (i >> 5) * CH + 512 + (i & 31);
            float v = gather_x(x, n, j);
            float a = fminf(fmaxf(v, 1e-4f), 1.0f);
            afac[t3] = a / (a + EPSV);
        }
    }
}

// ---------------------------------------------------------------------------
// votes via MFMA, M=64 blocking, ct-chunked staging (17 KB LDS).
__global__ __launch_bounds__(256) void votes_k(const ushort* __restrict__ p16,
                                               const ushort* __restrict__ w16,
                                               ushort* __restrict__ votes) {
    __shared__ ushort tile[64 * 136];   // 17 KB
    int mtt = blockIdx.x;         // 0..6
    int i = blockIdx.y;           // 0..287
    int t = threadIdx.x;
    int wv = t >> 6;
    int l = t & 63;
    int col = l & 15;
    int quad = l >> 4;

    int row_a = mtt * 64 + wv * 16 + col;
    v8h av = *(const v8h*)(p16 + ((size_t)(i * NPAD + row_a) << 5) + (quad << 3));

    for (int ch = 0; ch < 4; ++ch) {
#pragma unroll
        for (int c8 = 0; c8 < 8; ++c8) {
            int ct = ch * 8 + c8;
            v8h bv = *(const v8h*)(w16 + ((size_t)(i * CQ + ct * 16 + col) << 5) + (quad << 3));
            v4f acc = {0.f, 0.f, 0.f, 0.f};
            acc = __builtin_amdgcn_mfma_f32_16x16x32_f16(av, bv, acc, 0, 0, 0);
#pragma unroll
            for (int r = 0; r < 4; ++r)
                tile[(wv * 16 + quad * 4 + r) * 136 + c8 * 16 + col] =
                    __half_as_ushort(__float2half(acc[r]));
        }
        __syncthreads();
#pragma unroll
        for (int k = 0; k < 4; ++k) {
            int idx = k * 256 + t;
            int row = idx >> 4;
            int off = idx & 15;
            int n_out = mtt * 64 + row;
            if (n_out < NB) {
                uint4 d = *(const uint4*)&tile[row * 136 + off * 8];
                *(uint4*)(votes + (((size_t)n_out * NI + i) << 9) + ch * 128 + off * 8) = d;
            }
        }
        __syncthreads();
    }
}

// ---------------------------------------------------------------------------
// Fused dynamic routing, 3 passes. Block = n, 512 threads (8 waves) -- the
// empirically best block shape (r7: 47.6 us vs r9 768-thr: 55.9 us) -- now
// combined with the conflict-free [q*32+c] scratch layout (r9: 1.0M -> 94k
// SQ_LDS_BANK_CONFLICT). Lane: c = l&31, g = l>>5; wave wv step s handles
// i = (s*8+wv)*2+g. b_ij linear in history -> only cumulative vjr carried.
__global__ __launch_bounds__(RT_THREADS) void routing_k(const ushort* __restrict__ votes,
                                                        const float* __restrict__ afac,
                                                        float* __restrict__ out) {
    __shared__ float afs[NI];
    __shared__ float sred[RT_WAVES * CQ];   // 16 KB, [group][q*32+c]
    __shared__ float vj[CQ];                // [q*32+c]
    __shared__ float aout_s[NC];

    int n = blockIdx.x;
    int t = threadIdx.x;
    int wv = t >> 6;      // 0..7
    int l = t & 63;
    int c = l & 31;
    int g = l >> 5;

    if (t < NI) afs[t] = afac[n * NI + t];
    __syncthreads();

    const ushort* vb = votes + (size_t)n * NI * CQ;
    float vjr[16];    // cumulative sum of vj over past iters
    float sreg[16];

    for (int iter = 0; iter < 3; ++iter) {
#pragma unroll
        for (int q = 0; q < 16; ++q) sreg[q] = 0.f;

        // depth-2 prefetch: rows for s=0,1   (i = (s*8+wv)*2 + g)
        const uint4* r0 = (const uint4*)(vb + ((size_t)((0 * 8 + wv) * 2 + g) << 9) + (c << 4));
        uint4 a0 = r0[0], a1 = r0[1];
        const uint4* r1 = (const uint4*)(vb + ((size_t)((1 * 8 + wv) * 2 + g) << 9) + (c << 4));
        uint4 b0 = r1[0], b1 = r1[1];

#pragma clang loop unroll_count(2)
        for (int s = 0; s < 18; ++s) {
            int i = ((s << 3) + wv) * 2 + g;
            uint4 c0 = a0, c1 = a1;
            a0 = b0; a1 = b1;
            if (s + 2 < 18) {
                const uint4* rn = (const uint4*)(vb + ((size_t)((((s + 2) << 3) + wv) * 2 + g) << 9) + (c << 4));
                b0 = rn[0]; b1 = rn[1];
            }
            float vt[16];
            {
                float2 f;
                f = __half22float2(*(const __half2*)&c0.x); vt[0] = f.x;  vt[1] = f.y;
                f = __half22float2(*(const __half2*)&c0.y); vt[2] = f.x;  vt[3] = f.y;
                f = __half22float2(*(const __half2*)&c0.z); vt[4] = f.x;  vt[5] = f.y;
                f = __half22float2(*(const __half2*)&c0.w); vt[6] = f.x;  vt[7] = f.y;
                f = __half22float2(*(const __half2*)&c1.x); vt[8] = f.x;  vt[9] = f.y;
                f = __half22float2(*(const __half2*)&c1.y); vt[10] = f.x; vt[11] = f.y;
                f = __half22float2(*(const __half2*)&c1.z); vt[12] = f.x; vt[13] = f.y;
                f = __half22float2(*(const __half2*)&c1.w); vt[14] = f.x; vt[15] = f.y;
            }
            float cij;
            if (iter == 0) {
                cij = afs[i] * (1.0f / 32.0f);
            } else {
                float ah = 0.f;
#pragma unroll
                for (int q = 0; q < 16; ++q) ah += vt[q] * vjr[q];
                float e = __expf(ah);   // |b| <= ~0.7: no max-sub needed
                float ssum = e;
                ssum += __shfl_xor(ssum, 1);
                ssum += __shfl_xor(ssum, 2);
                ssum += __shfl_xor(ssum, 4);
                ssum += __shfl_xor(ssum, 8);
                ssum += __shfl_xor(ssum, 16);
                cij = e * __builtin_amdgcn_rcpf(ssum) * afs[i];
            }
#pragma unroll
            for (int q = 0; q < 16; ++q) sreg[q] += cij * vt[q];
        }

        // fold the two g-halves in-wave, then write 8 partial groups.
        // Layout [q*32+c]: lane c writes bank c -> conflict-free scalar stores.
#pragma unroll
        for (int q = 0; q < 16; ++q) sreg[q] += __shfl_xor(sreg[q], 32);
        if (g == 0) {
            float* sw = &sred[wv * CQ + c];
#pragma unroll
            for (int q = 0; q < 16; ++q) sw[q * 32] = sreg[q];
        }
        __syncthreads();
        {
            float ssum = 0.f;   // 512 threads == CQ columns
#pragma unroll
            for (int k = 0; k < RT_WAVES; ++k) ssum += sred[k * CQ + t];
            sred[t] = ssum;
        }
        __syncthreads();

        // squash (threads 0..31, one c each; element (c,q) at sred[q*32+c])
        if (t < NC) {
            float s2 = 0.f;
#pragma unroll
            for (int q = 0; q < 16; ++q) {
                float s = sred[q * 32 + t];
                s2 += s * s;
            }
            float f = (s2 / (1.f + s2)) / sqrtf(s2 + EPSV);
            float vn2 = 0.f;
#pragma unroll
            for (int q = 0; q < 16; ++q) {
                float v = f * sred[q * 32 + t];
                vj[q * 32 + t] = v;
                vn2 += v * v;
            }
            if (iter == 2) {
                float ao = sqrtf(vn2 + EPSV);
                ao = fminf(fmaxf(ao, 1e-4f), 1.f - 1e-4f);
                aout_s[t] = ao;
            }
        }
        __syncthreads();
        if (iter < 2) {
#pragma unroll
            for (int q = 0; q < 16; ++q) {
                float v = vj[q * 32 + c];   // bank c + broadcast pair: free
                vjr[q] = (iter == 0) ? v : vjr[q] + v;
            }
        }
    }

    // outputs: p_out, a_out, concat(out).  canonical idx t: c=t>>4, q=t&15
    {
        float v = vj[(t & 15) * 32 + (t >> 4)];
        out[(size_t)n * CQ + t] = v;
        out[OFF_CAT + (size_t)n * 544 + t] = v;
    }
    if (t < NC) {
        float ao = aout_s[t];
        out[OFF_AOUT + n * 32 + t] = ao;
        out[OFF_CAT + (size_t)n * 544 + 512 + t] = ao;
    }
}

// ---------------------------------------------------------------------------
extern "C" void kernel_launch(void* const* d_in, const int* in_sizes, int n_in,
                              void* d_out, int out_size, void* d_ws, size_t ws_size,
                              hipStream_t stream) {
    const float* x = (const float*)d_in[0];
    const float* wts = (const float*)d_in[1];
    float* out = (float*)d_out;
    float* ws = (float*)d_ws;

    float* afac = ws + OFF_AFAC;
    ushort* p16 = (ushort*)(ws + OFF_P16);
    ushort* w16 = (ushort*)(ws + OFF_W16);
    ushort* votes = (ushort*)(ws + OFF_VOT);

    hipLaunchKernelGGL(prep_k, dim3(PW_BLOCKS + P16_BLOCKS + AFAC_BLOCKS), dim3(256), 0, stream,
                       x, wts, p16, w16, afac);
    hipLaunchKernelGGL(votes_k, dim3(7, NI), dim3(256), 0, stream,
                       p16, w16, votes);
    hipLaunchKernelGGL(routing_k, dim3(NB), dim3(RT_THREADS), 0, stream,
                       votes, afac, out);
}

// Round 12
// 118.095 us; speedup vs baseline: 1.5030x; 1.2222x over previous
//
#include <hip/hip_runtime.h>
#include <hip/hip_fp16.h>
#include <math.h>

// Problem constants
#define NB 392      // n = b*oh*ow = 2*14*14
#define NI 288      // K*K*B = 9*32
#define NC 32       // C
#define NQ 16       // PSIZE
#define CQ 512      // NC*NQ
#define CH 544      // B*(PSIZE+1)
#define EPSV 1e-6f
#define NPAD 448    // n padded to 7 tiles of 64 rows

// votes are fp8 e4m3 scaled by 32; routing descales algebraically.
#define VSCALE 32.0f
#define VINV (1.0f / 32.0f)

// element counts (K=16 now -- no zero-pad; mfma 16x16x16 f16)
#define P16E (NI*NPAD*16)     // p16[i][n][16k] fp16 = 2,064,384
#define W16E (NI*CQ*16)       // w16[i][cq][16k] fp16 = 2,359,296
#define AFACE (NB*NI)         // afac floats = 112,896

// ws float offsets
#define OFF_AFAC 0
#define OFF_P16  (AFACE)
#define OFF_W16  (OFF_P16 + P16E/2)
#define OFF_VOT  (OFF_W16 + W16E/2)   // votes: NB*NI*512 bytes (fp8)

// out layout (floats)
#define OFF_AOUT 200704       // NB*CQ
#define OFF_CAT  213248       // OFF_AOUT + NB*NC

#define RT_THREADS 512
#define RT_WAVES 8

// merged prep grid split
#define PW_BLOCKS (NI*2)              // 576 transpose blocks (i, half-cq)
#define P16_BLOCKS (P16E/8/256)       // 1008 (uint4 stores)
#define AFAC_BLOCKS ((AFACE+255)/256) // 442

typedef _Float16 v4h __attribute__((ext_vector_type(4)));
typedef float v4f __attribute__((ext_vector_type(4)));
typedef float v2f __attribute__((ext_vector_type(2)));

// ---------------------------------------------------------------------------
// Gather from x via the unfold channel-major reinterpret.
__device__ __forceinline__ float gather_x(const float* __restrict__ x, int n, int j) {
    int c_idx = j / 9;
    int rem = j - c_idx * 9;
    int ki = rem / 3;
    int kj = rem - ki * 3;
    int b_ = n / 196;
    int rest = n - b_ * 196;
    int yy = rest / 14;
    int xx = rest - yy * 14;
    int iy = yy + ki - 1;
    int ix = xx + kj - 1;
    float v = 0.f;
    if ((unsigned)iy < 14u && (unsigned)ix < 14u)
        v = x[((b_ * 14 + iy) * 14 + ix) * CH + c_idx];
    return v;
}

// ---------------------------------------------------------------------------
// Merged prep: w16 transpose blocks + p16 gather blocks + afac blocks.
// All global stores uint4. K=16 layouts (half the bytes of round 10).
__global__ __launch_bounds__(256) void prep_k(const float* __restrict__ x,
                                              const float* __restrict__ wts,
                                              ushort* __restrict__ p16,
                                              ushort* __restrict__ w16,
                                              float* __restrict__ afac) {
    __shared__ float wl[4096];   // 16 KB (transpose blocks only)
    int b = blockIdx.x;
    int t = threadIdx.x;

    if (b < PW_BLOCKS) {
        // w16[i][cq][16k] <- wts[i][c][p][q]; this block: cq in [h*256, +256)
        int i = b >> 1, h = b & 1;
        const float4* src = (const float4*)(wts + (size_t)i * 8192 + h * 4096);
#pragma unroll
        for (int it = 0; it < 4; ++it)
            *(float4*)&wl[(it * 256 + t) * 4] = src[it * 256 + t];
        __syncthreads();
        uint4* dst = (uint4*)(w16 + (size_t)i * 8192 + h * 4096);  // 512 uint4
#pragma unroll
        for (int it = 0; it < 2; ++it) {
            int idx = it * 256 + t;          // (cl, m): m covers k = 8m..8m+7
            int cl = idx >> 1;
            int m = idx & 1;
            int base = (cl >> 4) * 256 + (cl & 15);
            uint v[4];
#pragma unroll
            for (int kk = 0; kk < 4; ++kk) {
                __half2 hh = __floats2half2_rn(wl[base + (8 * m + 2 * kk) * 16],
                                               wl[base + (8 * m + 2 * kk + 1) * 16]);
                v[kk] = *(uint*)&hh;
            }
            dst[cl * 2 + m] = make_uint4(v[0], v[1], v[2], v[3]);
        }
    } else if (b < PW_BLOCKS + P16_BLOCKS) {
        // p16[i][n][16k]: one uint4 (8 halves = half a row) per thread
        int idx = (b - PW_BLOCKS) * 256 + t;  // < P16E/8
        int half = idx & 1;
        int r = idx >> 1;
        int n = r % NPAD;
        int i = r / NPAD;
        uint4 val = {0u, 0u, 0u, 0u};
        if (n < NB) {
            int jb = (i >> 5) * CH + (i & 31) * 16 + half * 8;
            uint v[4];
#pragma unroll
            for (int kk = 0; kk < 4; ++kk) {
                __half2 hh = __floats2half2_rn(gather_x(x, n, jb + 2 * kk),
                                               gather_x(x, n, jb + 2 * kk + 1));
                v[kk] = *(uint*)&hh;
            }
            val = make_uint4(v[0], v[1], v[2], v[3]);
        }
        *(uint4*)(p16 + (size_t)idx * 8) = val;
    } else {
        int t3 = (b - PW_BLOCKS - P16_BLOCKS) * 256 + t;
        if (t3 < AFACE) {
            int i = t3 % NI;
            int n = t3 / NI;
            int j = (i >> 5) * CH + 512 + (i & 31);
            float v = gather_x(x, n, j);
            float a = fminf(fmaxf(v, 1e-4f), 1.0f);
            afac[t3] = a / (a + EPSV);
        }
    }
}

// ---------------------------------------------------------------------------
// votes via mfma 16x16x16 f16 (K=16 exact), fp8 e4m3 output scaled x32.
// Block (mtt, i), 256 threads = 4 waves, M=64. ct-chunked staging: 8 ct-tiles
// -> byte tile [64][144] (9.2 KB, 16B-aligned pitch), then 64 rows x 128 B
// contiguous global stores.
__global__ __launch_bounds__(256) void votes_k(const ushort* __restrict__ p16,
                                               const ushort* __restrict__ w16,
                                               uchar* __restrict__ votes) {
    __shared__ uchar tile[64 * 144];
    int mtt = blockIdx.x;         // 0..6
    int i = blockIdx.y;           // 0..287
    int t = threadIdx.x;
    int wv = t >> 6;
    int l = t & 63;
    int col = l & 15;
    int quad = l >> 4;

    int row_a = mtt * 64 + wv * 16 + col;
    v4h av = *(const v4h*)(p16 + ((size_t)(i * NPAD + row_a) << 4) + (quad << 2));

    for (int ch = 0; ch < 4; ++ch) {
#pragma unroll
        for (int c8 = 0; c8 < 8; ++c8) {
            int ct = ch * 8 + c8;
            v4h bv = *(const v4h*)(w16 + ((size_t)(i * CQ + ct * 16 + col) << 4) + (quad << 2));
            v4f acc = {0.f, 0.f, 0.f, 0.f};
            acc = __builtin_amdgcn_mfma_f32_16x16x16f16(av, bv, acc, 0, 0, 0);
            uint u01 = __builtin_amdgcn_cvt_pk_fp8_f32(acc[0] * VSCALE, acc[1] * VSCALE, 0, false);
            uint u23 = __builtin_amdgcn_cvt_pk_fp8_f32(acc[2] * VSCALE, acc[3] * VSCALE, 0, false);
            uchar* tb = &tile[(wv * 16 + quad * 4) * 144 + c8 * 16 + col];
            tb[0 * 144] = (uchar)(u01 & 0xFF);
            tb[1 * 144] = (uchar)((u01 >> 8) & 0xFF);
            tb[2 * 144] = (uchar)(u23 & 0xFF);
            tb[3 * 144] = (uchar)((u23 >> 8) & 0xFF);
        }
        __syncthreads();
        // 64 rows x 8 uint4 = 512 uint4; 2 steps. 8 lanes store one row's 128 B.
#pragma unroll
        for (int k = 0; k < 2; ++k) {
            int idx = k * 256 + t;
            int row = idx >> 3;
            int off = idx & 7;
            int n_out = mtt * 64 + row;
            if (n_out < NB) {
                uint4 d = *(const uint4*)&tile[row * 144 + off * 16];
                *(uint4*)(votes + (((size_t)n_out * NI + i) << 9) + ch * 128 + off * 16) = d;
            }
        }
        __syncthreads();
    }
}

// ---------------------------------------------------------------------------
// Fused dynamic routing, 3 passes over fp8 votes. Block = n, 512 threads.
// Lane: c = l&31, g = l>>5; wave wv step s handles i = (s*8+wv)*2+g.
// Scale folding: vjr stored pre-scaled (x 1/32) so the agreement dot uses raw
// fp8-decoded votes directly; s_j descaled by ONE multiply per thread per
// iter. Scratch layout [q*32+c] conflict-free. Depth-3 prefetch (1 uint4 =
// 16 fp8 per lane per step).
__global__ __launch_bounds__(RT_THREADS) void routing_k(const uchar* __restrict__ votes,
                                                        const float* __restrict__ afac,
                                                        float* __restrict__ out) {
    __shared__ float afs[NI];
    __shared__ float sred[RT_WAVES * CQ];   // 16 KB, [group][q*32+c]
    __shared__ float vj[CQ];                // [q*32+c]
    __shared__ float aout_s[NC];

    int n = blockIdx.x;
    int t = threadIdx.x;
    int wv = t >> 6;      // 0..7
    int l = t & 63;
    int c = l & 31;
    int g = l >> 5;

    if (t < NI) afs[t] = afac[n * NI + t];
    __syncthreads();

    const uchar* vb = votes + (size_t)n * NI * 512;
    float vjr[16];    // cumulative vj, PRE-SCALED by 1/32
    float sreg[16];

#define VROW(S) (((const uint4*)(vb + ((size_t)(((((S) << 3) + wv) << 1) + g) << 9)))[c])

    for (int iter = 0; iter < 3; ++iter) {
#pragma unroll
        for (int q = 0; q < 16; ++q) sreg[q] = 0.f;

        uint4 f0 = VROW(0), f1 = VROW(1), f2 = VROW(2);

#pragma clang loop unroll_count(2)
        for (int s = 0; s < 18; ++s) {
            int i = ((s << 3) + wv) * 2 + g;
            uint4 cur = f0;
            f0 = f1; f1 = f2;
            if (s + 3 < 18) f2 = VROW(s + 3);

            float vt[16];   // raw fp8-decoded (scaled x32 versions of votes)
            {
                v2f p;
                p = __builtin_amdgcn_cvt_pk_f32_fp8(cur.x, false); vt[0] = p[0];  vt[1] = p[1];
                p = __builtin_amdgcn_cvt_pk_f32_fp8(cur.x, true);  vt[2] = p[0];  vt[3] = p[1];
                p = __builtin_amdgcn_cvt_pk_f32_fp8(cur.y, false); vt[4] = p[0];  vt[5] = p[1];
                p = __builtin_amdgcn_cvt_pk_f32_fp8(cur.y, true);  vt[6] = p[0];  vt[7] = p[1];
                p = __builtin_amdgcn_cvt_pk_f32_fp8(cur.z, false); vt[8] = p[0];  vt[9] = p[1];
                p = __builtin_amdgcn_cvt_pk_f32_fp8(cur.z, true);  vt[10] = p[0]; vt[11] = p[1];
                p = __builtin_amdgcn_cvt_pk_f32_fp8(cur.w, false); vt[12] = p[0]; vt[13] = p[1];
                p = __builtin_amdgcn_cvt_pk_f32_fp8(cur.w, true);  vt[14] = p[0]; vt[15] = p[1];
            }
            float cij;
            if (iter == 0) {
                cij = afs[i] * (1.0f / 32.0f);
            } else {
                float ah = 0.f;   // vt(raw) . vjr(pre-scaled) == true dot
#pragma unroll
                for (int q = 0; q < 16; ++q) ah += vt[q] * vjr[q];
                float e = __expf(ah);
                float ssum = e;
                ssum += __shfl_xor(ssum, 1);
                ssum += __shfl_xor(ssum, 2);
                ssum += __shfl_xor(ssum, 4);
                ssum += __shfl_xor(ssum, 8);
                ssum += __shfl_xor(ssum, 16);
                cij = e * __builtin_amdgcn_rcpf(ssum) * afs[i];
            }
#pragma unroll
            for (int q = 0; q < 16; ++q) sreg[q] += cij * vt[q];
        }

        // fold g-halves, write 8 partial groups (layout [q*32+c]: bank==c)
#pragma unroll
        for (int q = 0; q < 16; ++q) sreg[q] += __shfl_xor(sreg[q], 32);
        if (g == 0) {
            float* sw = &sred[wv * CQ + c];
#pragma unroll
            for (int q = 0; q < 16; ++q) sw[q * 32] = sreg[q];
        }
        __syncthreads();
        {
            float ssum = 0.f;   // 512 threads == CQ columns
#pragma unroll
            for (int k = 0; k < RT_WAVES; ++k) ssum += sred[k * CQ + t];
            sred[t] = ssum * VINV;   // descale the x32 fp8 encoding ONCE
        }
        __syncthreads();

        // squash (threads 0..31, one c each; element (c,q) at sred[q*32+c])
        if (t < NC) {
            float s2 = 0.f;
#pragma unroll
            for (int q = 0; q < 16; ++q) {
                float s = sred[q * 32 + t];
                s2 += s * s;
            }
            float f = (s2 / (1.f + s2)) / sqrtf(s2 + EPSV);
            float vn2 = 0.f;
#pragma unroll
            for (int q = 0; q < 16; ++q) {
                float v = f * sred[q * 32 + t];
                vj[q * 32 + t] = v;
                vn2 += v * v;
            }
            if (iter == 2) {
                float ao = sqrtf(vn2 + EPSV);
                ao = fminf(fmaxf(ao, 1e-4f), 1.f - 1e-4f);
                aout_s[t] = ao;
            }
        }
        __syncthreads();
        if (iter < 2) {
#pragma unroll
            for (int q = 0; q < 16; ++q) {
                float v = vj[q * 32 + c] * VINV;   // pre-scale for the raw dot
                vjr[q] = (iter == 0) ? v : vjr[q] + v;
            }
        }
    }

    // outputs: p_out, a_out, concat(out).  canonical idx t: c=t>>4, q=t&15
    {
        float v = vj[(t & 15) * 32 + (t >> 4)];
        out[(size_t)n * CQ + t] = v;
        out[OFF_CAT + (size_t)n * 544 + t] = v;
    }
    if (t < NC) {
        float ao = aout_s[t];
        out[OFF_AOUT + n * 32 + t] = ao;
        out[OFF_CAT + (size_t)n * 544 + 512 + t] = ao;
    }
}

// ---------------------------------------------------------------------------
extern "C" void kernel_launch(void* const* d_in, const int* in_sizes, int n_in,
                              void* d_out, int out_size, void* d_ws, size_t ws_size,
                              hipStream_t stream) {
    const float* x = (const float*)d_in[0];
    const float* wts = (const float*)d_in[1];
    float* out = (float*)d_out;
    float* ws = (float*)d_ws;

    float* afac = ws + OFF_AFAC;
    ushort* p16 = (ushort*)(ws + OFF_P16);
    ushort* w16 = (ushort*)(ws + OFF_W16);
    uchar* votes = (uchar*)(ws + OFF_VOT);

    hipLaunchKernelGGL(prep_k, dim3(PW_BLOCKS + P16_BLOCKS + AFAC_BLOCKS), dim3(256), 0, stream,
                       x, wts, p16, w16, afac);
    hipLaunchKernelGGL(votes_k, dim3(7, NI), dim3(256), 0, stream,
                       p16, w16, votes);
    hipLaunchKernelGGL(routing_k, dim3(NB), dim3(RT_THREADS), 0, stream,
                       votes, afac, out);
}